// Round 9
// baseline (290.192 us; speedup 1.0000x reference)
//
#include <hip/hip_runtime.h>

#define EPS 1e-5f

typedef _Float16 half8 __attribute__((ext_vector_type(8)));
typedef float f32x16 __attribute__((ext_vector_type(16)));

// ---------------- L1: C = A(Mx16) @ B(Nx16)^T, f32, + col-stats epilogue ----------------
__global__ __launch_bounds__(256) void gemm_abt(const float* __restrict__ A,
                                                const float* __restrict__ B,
                                                float* __restrict__ C,
                                                int M, int N, int K,
                                                float* __restrict__ osum,
                                                float* __restrict__ osq) {
  __shared__ float As[16][68];
  __shared__ float Bs[16][68];
  const int t = threadIdx.x;
  const int tx = t & 15, ty = t >> 4;
  const int m0 = blockIdx.y * 64, n0 = blockIdx.x * 64;
  float acc[4][4] = {};
  for (int k0 = 0; k0 < K; k0 += 16) {
    __syncthreads();
    {
      const int r = t >> 2;
      const int kk = (t & 3) << 2;
      float4 av = *(const float4*)&A[(size_t)(m0 + r) * K + k0 + kk];
      As[kk + 0][r] = av.x; As[kk + 1][r] = av.y;
      As[kk + 2][r] = av.z; As[kk + 3][r] = av.w;
      float4 bv = *(const float4*)&B[(size_t)(n0 + r) * K + k0 + kk];
      Bs[kk + 0][r] = bv.x; Bs[kk + 1][r] = bv.y;
      Bs[kk + 2][r] = bv.z; Bs[kk + 3][r] = bv.w;
    }
    __syncthreads();
#pragma unroll
    for (int kk = 0; kk < 16; ++kk) {
      float4 a = *(const float4*)&As[kk][ty << 2];
      float4 b = *(const float4*)&Bs[kk][tx << 2];
      float av[4] = {a.x, a.y, a.z, a.w};
      float bv[4] = {b.x, b.y, b.z, b.w};
#pragma unroll
      for (int i = 0; i < 4; ++i)
#pragma unroll
        for (int j = 0; j < 4; ++j) acc[i][j] += av[i] * bv[j];
    }
  }
#pragma unroll
  for (int i = 0; i < 4; ++i) {
    float4 o = make_float4(acc[i][0], acc[i][1], acc[i][2], acc[i][3]);
    *(float4*)&C[(size_t)(m0 + (ty << 2) + i) * N + n0 + (tx << 2)] = o;
  }
  __syncthreads();
  float* sred = (float*)As;
  if (t < 128) sred[t] = 0.f;
  __syncthreads();
#pragma unroll
  for (int j = 0; j < 4; ++j) {
    float s = 0.f, sq = 0.f;
#pragma unroll
    for (int i = 0; i < 4; ++i) {
      float v = acc[i][j];
      s += v; sq += v * v;
    }
    atomicAdd(&sred[((tx << 2) + j) * 2 + 0], s);
    atomicAdd(&sred[((tx << 2) + j) * 2 + 1], sq);
  }
  __syncthreads();
  if (t < 64) {
    atomicAdd(&osum[n0 + t], sred[t * 2]);
    atomicAdd(&osq[n0 + t], sred[t * 2 + 1]);
  }
}

// ---------------- MFMA fp16 GEMM: C(f32) = T(A) @ B^T ----------------
template <int TRANS, bool STATS>
__global__ __launch_bounds__(256) void gemm16(const float* __restrict__ A,
                                              const float* __restrict__ B,
                                              float* __restrict__ C,
                                              int lda, int ldb, int ldc, int K,
                                              const float* __restrict__ s1,
                                              const float* __restrict__ s2,
                                              const float* __restrict__ g,
                                              const float* __restrict__ b,
                                              float invM,
                                              float* __restrict__ osum,
                                              float* __restrict__ osq) {
  __shared__ _Float16 As[128 * 64];
  __shared__ _Float16 Bs[128 * 64];
  __shared__ float scL[256], shL[256];
  const int t = threadIdx.x;
  const int m0 = blockIdx.y * 128, n0 = blockIdx.x * 128;
  const int w = t >> 6, l = t & 63;
  const int wm = w >> 1, wn = w & 1;
  const int lr = l & 31, lg = l >> 5;
  if (TRANS == 1) {
    if (t < K) {
      float mean = s1[t] * invM;
      float var = s2[t] * invM - mean * mean;
      float sc = g[t] * rsqrtf(var + EPS);
      scL[t] = sc;
      shL[t] = b[t] - mean * sc;
    }
  }
  f32x16 acc[2][2];
#pragma unroll
  for (int i = 0; i < 2; ++i)
#pragma unroll
    for (int j = 0; j < 2; ++j) acc[i][j] = (f32x16){0.f};
  for (int k0 = 0; k0 < K; k0 += 64) {
    __syncthreads();
#pragma unroll
    for (int i = 0; i < 4; ++i) {
      const int gq = i * 256 + t;
      const int f = gq >> 6, lp = gq & 63;
      const int row = (f >> 2) * 32 + (lp & 31);
      const int c = (f & 3) * 16 + (lp >> 5) * 8;
      const float* ap = A + (size_t)(m0 + row) * lda + k0 + c;
      float4 a4 = *(const float4*)ap, b4 = *(const float4*)(ap + 4);
      float va[8] = {a4.x, a4.y, a4.z, a4.w, b4.x, b4.y, b4.z, b4.w};
      if (TRANS == 1) {
#pragma unroll
        for (int j = 0; j < 8; ++j)
          va[j] = fmaxf(va[j] * scL[k0 + c + j] + shL[k0 + c + j], 0.f);
      }
      half8 h;
#pragma unroll
      for (int j = 0; j < 8; ++j) h[j] = (_Float16)va[j];
      *(half8*)(As + (size_t)gq * 8) = h;
      const float* bp = B + (size_t)(n0 + row) * ldb + k0 + c;
      float4 e4 = *(const float4*)bp, f4 = *(const float4*)(bp + 4);
      half8 hb;
      hb[0] = (_Float16)e4.x; hb[1] = (_Float16)e4.y; hb[2] = (_Float16)e4.z; hb[3] = (_Float16)e4.w;
      hb[4] = (_Float16)f4.x; hb[5] = (_Float16)f4.y; hb[6] = (_Float16)f4.z; hb[7] = (_Float16)f4.w;
      *(half8*)(Bs + (size_t)gq * 8) = hb;
    }
    __syncthreads();
#pragma unroll
    for (int ks = 0; ks < 4; ++ks) {
      half8 af[2], bf[2];
#pragma unroll
      for (int mb = 0; mb < 2; ++mb) {
        af[mb] = *(const half8*)(As + (size_t)(((wm * 2 + mb) * 4 + ks) * 64 + l) * 8);
        bf[mb] = *(const half8*)(Bs + (size_t)(((wn * 2 + mb) * 4 + ks) * 64 + l) * 8);
      }
#pragma unroll
      for (int mb = 0; mb < 2; ++mb)
#pragma unroll
        for (int nb = 0; nb < 2; ++nb)
          acc[mb][nb] = __builtin_amdgcn_mfma_f32_32x32x16_f16(af[mb], bf[nb], acc[mb][nb], 0, 0, 0);
    }
  }
#pragma unroll
  for (int mb = 0; mb < 2; ++mb)
#pragma unroll
    for (int nb = 0; nb < 2; ++nb)
#pragma unroll
      for (int r = 0; r < 16; ++r) {
        const int row = m0 + wm * 64 + mb * 32 + (r & 3) + 8 * (r >> 2) + 4 * lg;
        const int col = n0 + wn * 64 + nb * 32 + lr;
        C[(size_t)row * ldc + col] = acc[mb][nb][r];
      }
  if (STATS) {
    __syncthreads();
    float* sred = (float*)As;
    if (t < 256) sred[t] = 0.f;
    __syncthreads();
#pragma unroll
    for (int nb = 0; nb < 2; ++nb) {
      float s = 0.f, sq = 0.f;
#pragma unroll
      for (int mb = 0; mb < 2; ++mb)
#pragma unroll
        for (int r = 0; r < 16; ++r) {
          float v = acc[mb][nb][r];
          s += v; sq += v * v;
        }
      const int cl = wn * 64 + nb * 32 + lr;
      atomicAdd(&sred[cl * 2 + 0], s);
      atomicAdd(&sred[cl * 2 + 1], sq);
    }
    __syncthreads();
    if (t < 128) {
      atomicAdd(&osum[n0 + t], sred[t * 2]);
      atomicAdd(&osq[n0 + t], sred[t * 2 + 1]);
    }
  }
}

// ---------------- Gram partials on BN3(relu(y3)): 128 blocks x 128 rows ----------------
__global__ __launch_bounds__(256) void gram_kernel(const float* __restrict__ y3,
                                                   float* __restrict__ part,
                                                   const float* __restrict__ s3sum,
                                                   const float* __restrict__ s3sq,
                                                   const float* __restrict__ g3,
                                                   const float* __restrict__ b3,
                                                   float invE,
                                                   float* __restrict__ colsum) {
  __shared__ float xL[128 * 132];
  __shared__ float scL[128], shL[128];
  const int t = threadIdx.x, tx = t & 15, ty = t >> 4;
  if (t < 128) {
    float mean = s3sum[t] * invE;
    float var = s3sq[t] * invE - mean * mean;
    float sc = g3[t] * rsqrtf(var + EPS);
    scL[t] = sc;
    shL[t] = b3[t] - mean * sc;
  }
  __syncthreads();
  const int r0 = blockIdx.x * 128;
#pragma unroll
  for (int i = 0; i < 16; ++i) {
    int f4 = t + i * 256;
    int r = f4 >> 5;
    int c4 = (f4 & 31) << 2;
    float4 v = *(const float4*)&y3[(size_t)(r0 + r) * 128 + c4];
    v.x = fmaxf(v.x * scL[c4 + 0] + shL[c4 + 0], 0.f);
    v.y = fmaxf(v.y * scL[c4 + 1] + shL[c4 + 1], 0.f);
    v.z = fmaxf(v.z * scL[c4 + 2] + shL[c4 + 2], 0.f);
    v.w = fmaxf(v.w * scL[c4 + 3] + shL[c4 + 3], 0.f);
    *(float4*)&xL[r * 132 + c4] = v;
  }
  __syncthreads();
  float acc[8][8] = {};
  float csum[8] = {};
  for (int r = 0; r < 128; ++r) {
    float4 a0 = *(const float4*)&xL[r * 132 + ty * 8];
    float4 a1 = *(const float4*)&xL[r * 132 + ty * 8 + 4];
    float4 b0 = *(const float4*)&xL[r * 132 + tx * 8];
    float4 b1 = *(const float4*)&xL[r * 132 + tx * 8 + 4];
    float a[8] = {a0.x, a0.y, a0.z, a0.w, a1.x, a1.y, a1.z, a1.w};
    float b[8] = {b0.x, b0.y, b0.z, b0.w, b1.x, b1.y, b1.z, b1.w};
#pragma unroll
    for (int i = 0; i < 8; ++i)
#pragma unroll
      for (int j = 0; j < 8; ++j) acc[i][j] += a[i] * b[j];
    if (tx == ty) {
#pragma unroll
      for (int i = 0; i < 8; ++i) csum[i] += a[i];
    }
  }
  float* base = part + (size_t)blockIdx.x * 16384;
#pragma unroll
  for (int i = 0; i < 8; ++i)
#pragma unroll
    for (int j = 0; j < 8; ++j)
      base[(ty * 8 + i) * 128 + tx * 8 + j] = acc[i][j];
  if (tx == ty) {
#pragma unroll
    for (int i = 0; i < 8; ++i) atomicAdd(&colsum[ty * 8 + i], csum[i]);
  }
}

__global__ __launch_bounds__(256) void gram_reduce(const float* __restrict__ part,
                                                   float* __restrict__ out) {
  int idx = blockIdx.x * 256 + threadIdx.x;
  float s = 0.f;
  for (int b = 0; b < 128; ++b) s += part[(size_t)b * 16384 + idx];
  out[idx] = s;
}

// ---------------- finalize layer-4 BN; emit BTf (fp16 fragment-major) + t4 ----------------
__global__ __launch_bounds__(256) void w4_finalize(const float* __restrict__ W4,
                                                   const float* __restrict__ U,
                                                   const float* __restrict__ colsum3,
                                                   const float* __restrict__ g4,
                                                   const float* __restrict__ b4,
                                                   _Float16* __restrict__ BTf,
                                                   float* __restrict__ t4,
                                                   float invM) {
  const int r = (blockIdx.x * 256 + threadIdx.x) >> 6;
  const int lane = threadIdx.x & 63;
  const float* wp = W4 + (size_t)r * 128;
  const float* up = U + (size_t)r * 128;
  float p1 = 0.f, p2 = 0.f;
#pragma unroll
  for (int c0 = 0; c0 < 128; c0 += 64) {
    float wv = wp[c0 + lane];
    p1 += up[c0 + lane] * wv;
    p2 += colsum3[c0 + lane] * wv;
  }
#pragma unroll
  for (int off = 32; off > 0; off >>= 1) {
    p1 += __shfl_down(p1, off);
    p2 += __shfl_down(p2, off);
  }
  p1 = __shfl(p1, 0);
  p2 = __shfl(p2, 0);
  float m4 = p2 * invM;
  float q = p1 * invM;
  float s = g4[r] * rsqrtf(q - m4 * m4 + EPS);
  if (lane == 0) t4[r] = b4[r] - m4 * s;
  const int kout = r & 127, d = r >> 7;
  if (lane < 16) {
    const int ks = lane >> 1, lg = lane & 1;
    const float* cp = wp + lane * 8;
    float4 va = *(const float4*)cp, vb = *(const float4*)(cp + 4);
    half8 h;
    h[0] = (_Float16)(s * va.x); h[1] = (_Float16)(s * va.y);
    h[2] = (_Float16)(s * va.z); h[3] = (_Float16)(s * va.w);
    h[4] = (_Float16)(s * vb.x); h[5] = (_Float16)(s * vb.y);
    h[6] = (_Float16)(s * vb.z); h[7] = (_Float16)(s * vb.w);
    size_t off16 = (size_t)d * 16384 +
                   (size_t)((((kout >> 5) * 8 + ks) * 64) + (kout & 31) + lg * 32) * 8;
    *(half8*)(BTf + off16) = h;
  }
}

// ---------------- zgemm: barrier-free. 4 waves x disjoint 32n, B direct L2->regs ----------------
// tile 128e x 128n, KSPLIT=4 -> grid (4, E/128) = 512 blocks, 2 blocks/CU (9KB LDS).
// A (=BN3relu(y3)) dt-invariant in regs; B fragment slices coalesced from BTf; no K-loop sync.
__global__ __launch_bounds__(256, 2) void zgemm(const float* __restrict__ y3,
                                                const float* __restrict__ node,
                                                const int* __restrict__ eidx,
                                                const _Float16* __restrict__ BTf,
                                                const float* __restrict__ Tn,
                                                const float* __restrict__ s3sum,
                                                const float* __restrict__ s3sq,
                                                const float* __restrict__ g3,
                                                const float* __restrict__ b3,
                                                float invE,
                                                float* __restrict__ sums) {
  __shared__ _Float16 xiL[32 * 128];  // [d][e] 8KB
  __shared__ float scL[128], shL[128];
  const int t = threadIdx.x;
  const int e0 = blockIdx.y * 128;
  const int d0 = blockIdx.x * 32;
  const int w = t >> 6, l = t & 63;
  const int lr = l & 31, lg = l >> 5;
  // BN3 scale/shift table
  if (t < 128) {
    float mean = s3sum[t] * invE;
    float var = s3sq[t] * invE - mean * mean;
    float sc = g3[t] * rsqrtf(var + EPS);
    scL[t] = sc;
    shL[t] = b3[t] - mean * sc;
  }
  // stage xiL[d][e]
  {
    const int e = t >> 1, db = (t & 1) * 16;
    const int src = eidx[(e0 + e) * 2];
    const float* np = node + (size_t)src * 128 + d0 + db;
#pragma unroll
    for (int j = 0; j < 16; j += 4) {
      float4 v = *(const float4*)(np + j);
      xiL[(db + j + 0) * 128 + e] = (_Float16)v.x;
      xiL[(db + j + 1) * 128 + e] = (_Float16)v.y;
      xiL[(db + j + 2) * 128 + e] = (_Float16)v.z;
      xiL[(db + j + 3) * 128 + e] = (_Float16)v.w;
    }
  }
  __syncthreads();  // xiL/scL visible (only sync in the kernel)
  // A fragments with BN3+relu: all 128 e-rows per wave (4 row-blocks of 32)
  half8 xf[4][8];
#pragma unroll
  for (int mb = 0; mb < 4; ++mb) {
    const float* xp = y3 + (size_t)(e0 + mb * 32 + lr) * 128 + lg * 8;
#pragma unroll
    for (int ks = 0; ks < 8; ++ks) {
      const int c = ks * 16 + lg * 8;
      float4 a = *(const float4*)(xp + ks * 16);
      float4 b = *(const float4*)(xp + ks * 16 + 4);
      float va[8] = {a.x, a.y, a.z, a.w, b.x, b.y, b.z, b.w};
      half8 h;
#pragma unroll
      for (int j = 0; j < 8; ++j)
        h[j] = (_Float16)fmaxf(va[j] * scL[c + j] + shL[c + j], 0.f);
      xf[mb][ks] = h;
    }
  }
  f32x16 acc[4];
#pragma unroll
  for (int i = 0; i < 4; ++i) acc[i] = (f32x16){0.f};

  // per-wave B base: chunks w*8 .. w*8+7 (n-cols w*32 .. w*32+31), lane-coalesced
  const _Float16* bbase = BTf + ((size_t)(w * 8) * 64 + l) * 8;
  for (int dt = 0; dt < 32; ++dt) {
    const _Float16* bp = bbase + (size_t)(d0 + dt) * 16384;
    half8 bf[8];
#pragma unroll
    for (int ks = 0; ks < 8; ++ks) bf[ks] = *(const half8*)(bp + ks * 512);
    _Float16 xv[4];
#pragma unroll
    for (int mb = 0; mb < 4; ++mb) xv[mb] = xiL[dt * 128 + mb * 32 + lr];
#pragma unroll
    for (int ks = 0; ks < 8; ++ks) {
#pragma unroll
      for (int mb = 0; mb < 4; ++mb) {
        half8 xb = {xv[mb], xv[mb], xv[mb], xv[mb], xv[mb], xv[mb], xv[mb], xv[mb]};
        half8 a = xf[mb][ks] * xb;
        acc[mb] = __builtin_amdgcn_mfma_f32_32x32x16_f16(a, bf[ks], acc[mb], 0, 0, 0);
      }
    }
  }
  // epilogue: scatter into sums[dst]; split 0 adds Tn[src]
  const bool add_t = (blockIdx.x == 0);
  const int col = w * 32 + lr;
#pragma unroll
  for (int mb = 0; mb < 4; ++mb)
#pragma unroll
    for (int r = 0; r < 16; ++r) {
      const int e = e0 + mb * 32 + (r & 3) + 8 * (r >> 2) + 4 * lg;
      const int dn = eidx[e * 2 + 1];
      float v = acc[mb][r];
      if (add_t) v += Tn[(size_t)eidx[e * 2] * 128 + col];
      atomicAdd(&sums[(size_t)dn * 128 + col], v);
    }
}

// ---------------- Tn = node @ t4mat  (+ fused edge-count) ----------------
__global__ __launch_bounds__(128) void t4n_kernel(const float* __restrict__ node,
                                                  const float* __restrict__ t4,
                                                  float* __restrict__ Tn,
                                                  const int* __restrict__ eidx,
                                                  float* __restrict__ cnt, int E) {
  __shared__ float nodeL[8][128];
  const int k = threadIdx.x;
  const int n0 = blockIdx.x * 8;
  {
    int e = blockIdx.x * 32 + k;
    if (k < 32 && e < E) atomicAdd(&cnt[eidx[e * 2 + 1]], 1.0f);
  }
#pragma unroll
  for (int j = 0; j < 8; ++j) nodeL[j][k] = node[(size_t)(n0 + j) * 128 + k];
  __syncthreads();
  float acc[8] = {};
  for (int d = 0; d < 128; ++d) {
    float wv = t4[d * 128 + k];
#pragma unroll
    for (int j = 0; j < 8; ++j) acc[j] += nodeL[j][d] * wv;
  }
#pragma unroll
  for (int j = 0; j < 8; ++j) Tn[(size_t)(n0 + j) * 128 + k] = acc[j];
}

// ---------------- GRU gates: bx<3 -> gi (mrelu A), else gh ----------------
__global__ __launch_bounds__(256) void gru_gates(const float* __restrict__ sums,
                                                 const float* __restrict__ cnt,
                                                 const float* __restrict__ bias,
                                                 const float* __restrict__ h0,
                                                 const float* __restrict__ Wih,
                                                 const float* __restrict__ Whh,
                                                 float* __restrict__ gi,
                                                 float* __restrict__ gh) {
  __shared__ _Float16 As[128 * 64];
  __shared__ _Float16 Bs[128 * 64];
  const bool isgh = blockIdx.x >= 3;
  const float* A = isgh ? h0 : sums;
  const float* B = isgh ? Whh : Wih;
  float* C = isgh ? gh : gi;
  const int n0 = (isgh ? blockIdx.x - 3 : blockIdx.x) * 128;
  const int m0 = blockIdx.y * 128;
  const int t = threadIdx.x;
  const int w = t >> 6, l = t & 63;
  const int wm = w >> 1, wn = w & 1;
  const int lr = l & 31, lg = l >> 5;
  f32x16 acc[2][2];
#pragma unroll
  for (int i = 0; i < 2; ++i)
#pragma unroll
    for (int j = 0; j < 2; ++j) acc[i][j] = (f32x16){0.f};
  for (int k0 = 0; k0 < 128; k0 += 64) {
    __syncthreads();
#pragma unroll
    for (int i = 0; i < 4; ++i) {
      const int gq = i * 256 + t;
      const int f = gq >> 6, lp = gq & 63;
      const int row = (f >> 2) * 32 + (lp & 31);
      const int c = (f & 3) * 16 + (lp >> 5) * 8;
      const float* ap = A + (size_t)(m0 + row) * 128 + k0 + c;
      float4 a4 = *(const float4*)ap, b4 = *(const float4*)(ap + 4);
      float va[8] = {a4.x, a4.y, a4.z, a4.w, b4.x, b4.y, b4.z, b4.w};
      if (!isgh) {
        float rc = 1.f / fmaxf(cnt[m0 + row], 1.f);
#pragma unroll
        for (int j = 0; j < 8; ++j) va[j] = fmaxf(va[j] * rc + bias[k0 + c + j], 0.f);
      }
      half8 h;
#pragma unroll
      for (int j = 0; j < 8; ++j) h[j] = (_Float16)va[j];
      *(half8*)(As + (size_t)gq * 8) = h;
      const float* bp = B + (size_t)(n0 + row) * 128 + k0 + c;
      float4 e4 = *(const float4*)bp, f4 = *(const float4*)(bp + 4);
      half8 hb;
      hb[0] = (_Float16)e4.x; hb[1] = (_Float16)e4.y; hb[2] = (_Float16)e4.z; hb[3] = (_Float16)e4.w;
      hb[4] = (_Float16)f4.x; hb[5] = (_Float16)f4.y; hb[6] = (_Float16)f4.z; hb[7] = (_Float16)f4.w;
      *(half8*)(Bs + (size_t)gq * 8) = hb;
    }
    __syncthreads();
#pragma unroll
    for (int ks = 0; ks < 4; ++ks) {
      half8 af[2], bf[2];
#pragma unroll
      for (int mb = 0; mb < 2; ++mb) {
        af[mb] = *(const half8*)(As + (size_t)(((wm * 2 + mb) * 4 + ks) * 64 + l) * 8);
        bf[mb] = *(const half8*)(Bs + (size_t)(((wn * 2 + mb) * 4 + ks) * 64 + l) * 8);
      }
#pragma unroll
      for (int mb = 0; mb < 2; ++mb)
#pragma unroll
        for (int nb = 0; nb < 2; ++nb)
          acc[mb][nb] = __builtin_amdgcn_mfma_f32_32x32x16_f16(af[mb], bf[nb], acc[mb][nb], 0, 0, 0);
    }
  }
#pragma unroll
  for (int mb = 0; mb < 2; ++mb)
#pragma unroll
    for (int nb = 0; nb < 2; ++nb)
#pragma unroll
      for (int r = 0; r < 16; ++r) {
        const int row = m0 + wm * 64 + mb * 32 + (r & 3) + 8 * (r >> 2) + 4 * lg;
        const int col = n0 + wn * 64 + nb * 32 + lr;
        C[(size_t)row * 384 + col] = acc[mb][nb][r];
      }
}

// ---------------- GRU finalize ----------------
__global__ __launch_bounds__(256) void gru_finalize(const float* __restrict__ gi,
                                                    const float* __restrict__ gh,
                                                    const float* __restrict__ h0,
                                                    const float* __restrict__ bih,
                                                    const float* __restrict__ bhh,
                                                    float* __restrict__ out, int Nn) {
  int idx = blockIdx.x * 256 + threadIdx.x;
  int n = idx >> 7, k = idx & 127;
  const float* gin = gi + (size_t)n * 384;
  const float* ghn = gh + (size_t)n * 384;
  float r = 1.f / (1.f + expf(-(gin[k] + bih[k] + ghn[k] + bhh[k])));
  float z = 1.f / (1.f + expf(-(gin[128 + k] + bih[128 + k] + ghn[128 + k] + bhh[128 + k])));
  float nn = tanhf(gin[256 + k] + bih[256 + k] + r * (ghn[256 + k] + bhh[256 + k]));
  float h = h0[idx];
  float hn = (1.f - z) * nn + z * h;
  out[idx] = hn;
  out[idx + (size_t)Nn * 128] = hn;
}

extern "C" void kernel_launch(void* const* d_in, const int* in_sizes, int n_in,
                              void* d_out, int out_size, void* d_ws, size_t ws_size,
                              hipStream_t stream) {
  const float* node = (const float*)d_in[0];
  const int* eidx = (const int*)d_in[1];
  const float* edge = (const float*)d_in[2];
  const float* hidden = (const float*)d_in[3];
  const float* W1 = (const float*)d_in[4];
  const float* g1 = (const float*)d_in[5];
  const float* b1 = (const float*)d_in[6];
  const float* W2 = (const float*)d_in[7];
  const float* g2 = (const float*)d_in[8];
  const float* b2 = (const float*)d_in[9];
  const float* W3 = (const float*)d_in[10];
  const float* g3 = (const float*)d_in[11];
  const float* b3 = (const float*)d_in[12];
  const float* W4 = (const float*)d_in[13];
  const float* g4 = (const float*)d_in[14];
  const float* b4 = (const float*)d_in[15];
  const float* bias = (const float*)d_in[16];
  const float* Wih = (const float*)d_in[17];
  const float* Whh = (const float*)d_in[18];
  const float* bih = (const float*)d_in[19];
  const float* bhh = (const float*)d_in[20];
  float* out = (float*)d_out;

  const int Nn = in_sizes[0] / 128;   // 4096
  const int E = in_sizes[2] / 16;     // 16384
  const float invE = 1.0f / (float)E;

  float* ws = (float*)d_ws;
  float* ybuf1 = ws + 0;                       // E x 256 (y1 raw) -> gram partials 128x16384
  float* ybuf2 = ws + 4194304;                 // E x 256 (y2 raw) -> U -> gi/gh
  float* y3buf = ws + 8388608;                 // E x 128 (y3 RAW, BN3 fused in consumers)
  _Float16* BTf = (_Float16*)(ws + 10485760);  // 128 tiles x 16384 halves (4MB)
  float* t4 = ws + 11534336;                   // 16384
  float* stats = ws + 11550720;                // stat1,stat2,stat3 (3x512) + colsum3 (128)
  float* G3 = ws + 11552512;                   // 16384
  float* sums = ws + 11568896;                 // Nn x 128
  float* cnt = ws + 12093184;                  // Nn
  float* Tn = ws + 12097280;                   // Nn x 128
  float* stat1 = stats, *stat2 = stats + 512, *stat3 = stats + 1024;
  float* colsum3 = stats + 1536;
  float* gpart = ybuf1;                        // 128 x 16384
  float* U = ybuf2;                            // 16384 x 128
  float* gi = ybuf2;                           // 4096 x 384
  float* gh = ybuf2 + 1572864;                 // 4096 x 384

  hipMemsetAsync(stats, 0, 1664 * sizeof(float), stream);
  hipMemsetAsync(sums, 0, ((size_t)Nn * 128 + Nn) * sizeof(float), stream);

  // L1: y1 = edge @ W1^T (+stats1)
  gemm_abt<<<dim3(4, E / 64), 256, 0, stream>>>(edge, W1, ybuf1, E, 256, 16, stat1, stat1 + 256);
  // L2: y2 = bn1relu(y1) @ W2^T (+stats2)
  gemm16<1, true><<<dim3(2, E / 128), 256, 0, stream>>>(ybuf1, W2, ybuf2, 256, 256, 256, 256,
                                                        stat1, stat1 + 256, g1, b1, invE,
                                                        stat2, stat2 + 256);
  // L3: y3 = bn2relu(y2) @ W3^T (+stats3)
  gemm16<1, true><<<dim3(1, E / 128), 256, 0, stream>>>(ybuf2, W3, y3buf, 256, 256, 128, 256,
                                                        stat2, stat2 + 256, g2, b2, invE,
                                                        stat3, stat3 + 256);

  // Gram on bn3relu(y3) (fused) -> partials + colsum3 -> reduce
  gram_kernel<<<E / 128, 256, 0, stream>>>(y3buf, gpart, stat3, stat3 + 256, g3, b3, invE,
                                           colsum3);
  gram_reduce<<<64, 256, 0, stream>>>(gpart, G3);

  // U = W4 @ G3
  gemm16<0, false><<<dim3(1, 16384 / 128), 256, 0, stream>>>(W4, G3, U, 128, 128, 128, 128,
                                                             nullptr, nullptr, nullptr, nullptr,
                                                             0.f, nullptr, nullptr);
  w4_finalize<<<16384 / 4, 256, 0, stream>>>(W4, U, colsum3, g4, b4, BTf, t4, invE);
  t4n_kernel<<<Nn / 8, 128, 0, stream>>>(node, t4, Tn, eidx, cnt, E);

  // barrier-free fused message GEMM with direct scatter
  zgemm<<<dim3(4, E / 128), 256, 0, stream>>>(y3buf, node, eidx, BTf, Tn,
                                              stat3, stat3 + 256, g3, b3, invE, sums);

  // GRU
  gru_gates<<<dim3(6, Nn / 128), 256, 0, stream>>>(sums, cnt, bias, hidden, Wih, Whh, gi, gh);
  gru_finalize<<<Nn * 128 / 256, 256, 0, stream>>>(gi, gh, hidden, bih, bhh, out, Nn);
}

// Round 10
// 256.833 us; speedup vs baseline: 1.1299x; 1.1299x over previous
//
#include <hip/hip_runtime.h>

#define EPS 1e-5f

typedef _Float16 half8 __attribute__((ext_vector_type(8)));
typedef float f32x16 __attribute__((ext_vector_type(16)));

__device__ __forceinline__ void gload16(const void* g, void* l) {
  __builtin_amdgcn_global_load_lds((const __attribute__((address_space(1))) void*)g,
                                   (__attribute__((address_space(3))) void*)l, 16, 0, 0);
}

// ---------------- L1: C = A(Mx16) @ B(Nx16)^T, f32, + col-stats epilogue ----------------
__global__ __launch_bounds__(256) void gemm_abt(const float* __restrict__ A,
                                                const float* __restrict__ B,
                                                float* __restrict__ C,
                                                int M, int N, int K,
                                                float* __restrict__ osum,
                                                float* __restrict__ osq) {
  __shared__ float As[16][68];
  __shared__ float Bs[16][68];
  const int t = threadIdx.x;
  const int tx = t & 15, ty = t >> 4;
  const int m0 = blockIdx.y * 64, n0 = blockIdx.x * 64;
  float acc[4][4] = {};
  for (int k0 = 0; k0 < K; k0 += 16) {
    __syncthreads();
    {
      const int r = t >> 2;
      const int kk = (t & 3) << 2;
      float4 av = *(const float4*)&A[(size_t)(m0 + r) * K + k0 + kk];
      As[kk + 0][r] = av.x; As[kk + 1][r] = av.y;
      As[kk + 2][r] = av.z; As[kk + 3][r] = av.w;
      float4 bv = *(const float4*)&B[(size_t)(n0 + r) * K + k0 + kk];
      Bs[kk + 0][r] = bv.x; Bs[kk + 1][r] = bv.y;
      Bs[kk + 2][r] = bv.z; Bs[kk + 3][r] = bv.w;
    }
    __syncthreads();
#pragma unroll
    for (int kk = 0; kk < 16; ++kk) {
      float4 a = *(const float4*)&As[kk][ty << 2];
      float4 b = *(const float4*)&Bs[kk][tx << 2];
      float av[4] = {a.x, a.y, a.z, a.w};
      float bv[4] = {b.x, b.y, b.z, b.w};
#pragma unroll
      for (int i = 0; i < 4; ++i)
#pragma unroll
        for (int j = 0; j < 4; ++j) acc[i][j] += av[i] * bv[j];
    }
  }
#pragma unroll
  for (int i = 0; i < 4; ++i) {
    float4 o = make_float4(acc[i][0], acc[i][1], acc[i][2], acc[i][3]);
    *(float4*)&C[(size_t)(m0 + (ty << 2) + i) * N + n0 + (tx << 2)] = o;
  }
  __syncthreads();
  float* sred = (float*)As;
  if (t < 128) sred[t] = 0.f;
  __syncthreads();
#pragma unroll
  for (int j = 0; j < 4; ++j) {
    float s = 0.f, sq = 0.f;
#pragma unroll
    for (int i = 0; i < 4; ++i) {
      float v = acc[i][j];
      s += v; sq += v * v;
    }
    atomicAdd(&sred[((tx << 2) + j) * 2 + 0], s);
    atomicAdd(&sred[((tx << 2) + j) * 2 + 1], sq);
  }
  __syncthreads();
  if (t < 64) {
    atomicAdd(&osum[n0 + t], sred[t * 2]);
    atomicAdd(&osq[n0 + t], sred[t * 2 + 1]);
  }
}

// ---------------- MFMA fp16 GEMM: C(f32) = T(A) @ B^T ----------------
template <int TRANS, bool STATS>
__global__ __launch_bounds__(256) void gemm16(const float* __restrict__ A,
                                              const float* __restrict__ B,
                                              float* __restrict__ C,
                                              int lda, int ldb, int ldc, int K,
                                              const float* __restrict__ s1,
                                              const float* __restrict__ s2,
                                              const float* __restrict__ g,
                                              const float* __restrict__ b,
                                              float invM,
                                              float* __restrict__ osum,
                                              float* __restrict__ osq) {
  __shared__ _Float16 As[128 * 64];
  __shared__ _Float16 Bs[128 * 64];
  __shared__ float scL[256], shL[256];
  const int t = threadIdx.x;
  const int m0 = blockIdx.y * 128, n0 = blockIdx.x * 128;
  const int w = t >> 6, l = t & 63;
  const int wm = w >> 1, wn = w & 1;
  const int lr = l & 31, lg = l >> 5;
  if (TRANS == 1) {
    if (t < K) {
      float mean = s1[t] * invM;
      float var = s2[t] * invM - mean * mean;
      float sc = g[t] * rsqrtf(var + EPS);
      scL[t] = sc;
      shL[t] = b[t] - mean * sc;
    }
  }
  f32x16 acc[2][2];
#pragma unroll
  for (int i = 0; i < 2; ++i)
#pragma unroll
    for (int j = 0; j < 2; ++j) acc[i][j] = (f32x16){0.f};
  for (int k0 = 0; k0 < K; k0 += 64) {
    __syncthreads();
#pragma unroll
    for (int i = 0; i < 4; ++i) {
      const int gq = i * 256 + t;
      const int f = gq >> 6, lp = gq & 63;
      const int row = (f >> 2) * 32 + (lp & 31);
      const int c = (f & 3) * 16 + (lp >> 5) * 8;
      const float* ap = A + (size_t)(m0 + row) * lda + k0 + c;
      float4 a4 = *(const float4*)ap, b4 = *(const float4*)(ap + 4);
      float va[8] = {a4.x, a4.y, a4.z, a4.w, b4.x, b4.y, b4.z, b4.w};
      if (TRANS == 1) {
#pragma unroll
        for (int j = 0; j < 8; ++j)
          va[j] = fmaxf(va[j] * scL[k0 + c + j] + shL[k0 + c + j], 0.f);
      }
      half8 h;
#pragma unroll
      for (int j = 0; j < 8; ++j) h[j] = (_Float16)va[j];
      *(half8*)(As + (size_t)gq * 8) = h;
      const float* bp = B + (size_t)(n0 + row) * ldb + k0 + c;
      float4 e4 = *(const float4*)bp, f4 = *(const float4*)(bp + 4);
      half8 hb;
      hb[0] = (_Float16)e4.x; hb[1] = (_Float16)e4.y; hb[2] = (_Float16)e4.z; hb[3] = (_Float16)e4.w;
      hb[4] = (_Float16)f4.x; hb[5] = (_Float16)f4.y; hb[6] = (_Float16)f4.z; hb[7] = (_Float16)f4.w;
      *(half8*)(Bs + (size_t)gq * 8) = hb;
    }
    __syncthreads();
#pragma unroll
    for (int ks = 0; ks < 4; ++ks) {
      half8 af[2], bf[2];
#pragma unroll
      for (int mb = 0; mb < 2; ++mb) {
        af[mb] = *(const half8*)(As + (size_t)(((wm * 2 + mb) * 4 + ks) * 64 + l) * 8);
        bf[mb] = *(const half8*)(Bs + (size_t)(((wn * 2 + mb) * 4 + ks) * 64 + l) * 8);
      }
#pragma unroll
      for (int mb = 0; mb < 2; ++mb)
#pragma unroll
        for (int nb = 0; nb < 2; ++nb)
          acc[mb][nb] = __builtin_amdgcn_mfma_f32_32x32x16_f16(af[mb], bf[nb], acc[mb][nb], 0, 0, 0);
    }
  }
#pragma unroll
  for (int mb = 0; mb < 2; ++mb)
#pragma unroll
    for (int nb = 0; nb < 2; ++nb)
#pragma unroll
      for (int r = 0; r < 16; ++r) {
        const int row = m0 + wm * 64 + mb * 32 + (r & 3) + 8 * (r >> 2) + 4 * lg;
        const int col = n0 + wn * 64 + nb * 32 + lr;
        C[(size_t)row * ldc + col] = acc[mb][nb][r];
      }
  if (STATS) {
    __syncthreads();
    float* sred = (float*)As;
    if (t < 256) sred[t] = 0.f;
    __syncthreads();
#pragma unroll
    for (int nb = 0; nb < 2; ++nb) {
      float s = 0.f, sq = 0.f;
#pragma unroll
      for (int mb = 0; mb < 2; ++mb)
#pragma unroll
        for (int r = 0; r < 16; ++r) {
          float v = acc[mb][nb][r];
          s += v; sq += v * v;
        }
      const int cl = wn * 64 + nb * 32 + lr;
      atomicAdd(&sred[cl * 2 + 0], s);
      atomicAdd(&sred[cl * 2 + 1], sq);
    }
    __syncthreads();
    if (t < 128) {
      atomicAdd(&osum[n0 + t], sred[t * 2]);
      atomicAdd(&osq[n0 + t], sred[t * 2 + 1]);
    }
  }
}

// ---------------- Gram partials on BN3(relu(y3)): 128 blocks x 128 rows ----------------
__global__ __launch_bounds__(256) void gram_kernel(const float* __restrict__ y3,
                                                   float* __restrict__ part,
                                                   const float* __restrict__ s3sum,
                                                   const float* __restrict__ s3sq,
                                                   const float* __restrict__ g3,
                                                   const float* __restrict__ b3,
                                                   float invE,
                                                   float* __restrict__ colsum) {
  __shared__ float xL[128 * 132];
  __shared__ float scL[128], shL[128];
  const int t = threadIdx.x, tx = t & 15, ty = t >> 4;
  if (t < 128) {
    float mean = s3sum[t] * invE;
    float var = s3sq[t] * invE - mean * mean;
    float sc = g3[t] * rsqrtf(var + EPS);
    scL[t] = sc;
    shL[t] = b3[t] - mean * sc;
  }
  __syncthreads();
  const int r0 = blockIdx.x * 128;
#pragma unroll
  for (int i = 0; i < 16; ++i) {
    int f4 = t + i * 256;
    int r = f4 >> 5;
    int c4 = (f4 & 31) << 2;
    float4 v = *(const float4*)&y3[(size_t)(r0 + r) * 128 + c4];
    v.x = fmaxf(v.x * scL[c4 + 0] + shL[c4 + 0], 0.f);
    v.y = fmaxf(v.y * scL[c4 + 1] + shL[c4 + 1], 0.f);
    v.z = fmaxf(v.z * scL[c4 + 2] + shL[c4 + 2], 0.f);
    v.w = fmaxf(v.w * scL[c4 + 3] + shL[c4 + 3], 0.f);
    *(float4*)&xL[r * 132 + c4] = v;
  }
  __syncthreads();
  float acc[8][8] = {};
  float csum[8] = {};
  for (int r = 0; r < 128; ++r) {
    float4 a0 = *(const float4*)&xL[r * 132 + ty * 8];
    float4 a1 = *(const float4*)&xL[r * 132 + ty * 8 + 4];
    float4 b0 = *(const float4*)&xL[r * 132 + tx * 8];
    float4 b1 = *(const float4*)&xL[r * 132 + tx * 8 + 4];
    float a[8] = {a0.x, a0.y, a0.z, a0.w, a1.x, a1.y, a1.z, a1.w};
    float b[8] = {b0.x, b0.y, b0.z, b0.w, b1.x, b1.y, b1.z, b1.w};
#pragma unroll
    for (int i = 0; i < 8; ++i)
#pragma unroll
      for (int j = 0; j < 8; ++j) acc[i][j] += a[i] * b[j];
    if (tx == ty) {
#pragma unroll
      for (int i = 0; i < 8; ++i) csum[i] += a[i];
    }
  }
  float* base = part + (size_t)blockIdx.x * 16384;
#pragma unroll
  for (int i = 0; i < 8; ++i)
#pragma unroll
    for (int j = 0; j < 8; ++j)
      base[(ty * 8 + i) * 128 + tx * 8 + j] = acc[i][j];
  if (tx == ty) {
#pragma unroll
    for (int i = 0; i < 8; ++i) atomicAdd(&colsum[ty * 8 + i], csum[i]);
  }
}

__global__ __launch_bounds__(256) void gram_reduce(const float* __restrict__ part,
                                                   float* __restrict__ out) {
  int idx = blockIdx.x * 256 + threadIdx.x;
  float s = 0.f;
  for (int b = 0; b < 128; ++b) s += part[(size_t)b * 16384 + idx];
  out[idx] = s;
}

// ---------------- finalize layer-4 BN; emit BTf (fp16 fragment-major) + t4 ----------------
__global__ __launch_bounds__(256) void w4_finalize(const float* __restrict__ W4,
                                                   const float* __restrict__ U,
                                                   const float* __restrict__ colsum3,
                                                   const float* __restrict__ g4,
                                                   const float* __restrict__ b4,
                                                   _Float16* __restrict__ BTf,
                                                   float* __restrict__ t4,
                                                   float invM) {
  const int r = (blockIdx.x * 256 + threadIdx.x) >> 6;
  const int lane = threadIdx.x & 63;
  const float* wp = W4 + (size_t)r * 128;
  const float* up = U + (size_t)r * 128;
  float p1 = 0.f, p2 = 0.f;
#pragma unroll
  for (int c0 = 0; c0 < 128; c0 += 64) {
    float wv = wp[c0 + lane];
    p1 += up[c0 + lane] * wv;
    p2 += colsum3[c0 + lane] * wv;
  }
#pragma unroll
  for (int off = 32; off > 0; off >>= 1) {
    p1 += __shfl_down(p1, off);
    p2 += __shfl_down(p2, off);
  }
  p1 = __shfl(p1, 0);
  p2 = __shfl(p2, 0);
  float m4 = p2 * invM;
  float q = p1 * invM;
  float s = g4[r] * rsqrtf(q - m4 * m4 + EPS);
  if (lane == 0) t4[r] = b4[r] - m4 * s;
  const int kout = r & 127, d = r >> 7;
  if (lane < 16) {
    const int ks = lane >> 1, lg = lane & 1;
    const float* cp = wp + lane * 8;
    float4 va = *(const float4*)cp, vb = *(const float4*)(cp + 4);
    half8 h;
    h[0] = (_Float16)(s * va.x); h[1] = (_Float16)(s * va.y);
    h[2] = (_Float16)(s * va.z); h[3] = (_Float16)(s * va.w);
    h[4] = (_Float16)(s * vb.x); h[5] = (_Float16)(s * vb.y);
    h[6] = (_Float16)(s * vb.z); h[7] = (_Float16)(s * vb.w);
    size_t off16 = (size_t)d * 16384 +
                   (size_t)((((kout >> 5) * 8 + ks) * 64) + (kout & 31) + lg * 32) * 8;
    *(half8*)(BTf + off16) = h;
  }
}

// ---------------- zgemm: R8 layout + DMA-staged B (no write phase, 1 barrier/dt) ----------------
// 2x2 waves of 64e x 64n, tile 128e x 128n, KSPLIT=4 -> grid (4, E/128), 2 blocks/CU.
__global__ __launch_bounds__(256, 2) void zgemm(const float* __restrict__ y3,
                                                const float* __restrict__ node,
                                                const int* __restrict__ eidx,
                                                const _Float16* __restrict__ BTf,
                                                const float* __restrict__ Tn,
                                                const float* __restrict__ s3sum,
                                                const float* __restrict__ s3sq,
                                                const float* __restrict__ g3,
                                                const float* __restrict__ b3,
                                                float invE,
                                                float* __restrict__ sums) {
  __shared__ __align__(16) _Float16 Bs[2][16384];  // 2 x 32KB fragment-major
  __shared__ _Float16 xiL[32 * 128];               // [d][e] 8KB
  __shared__ float scL[128], shL[128];
  const int t = threadIdx.x;
  const int e0 = blockIdx.y * 128;
  const int d0 = blockIdx.x * 32;
  const int w = t >> 6, l = t & 63;
  const int wm = w >> 1, wn = w & 1;
  const int lr = l & 31, lg = l >> 5;
  // BN3 scale/shift table
  if (t < 128) {
    float mean = s3sum[t] * invE;
    float var = s3sq[t] * invE - mean * mean;
    float sc = g3[t] * rsqrtf(var + EPS);
    scL[t] = sc;
    shL[t] = b3[t] - mean * sc;
  }
  // stage xiL[d][e]
  {
    const int e = t >> 1, db = (t & 1) * 16;
    const int src = eidx[(e0 + e) * 2];
    const float* np = node + (size_t)src * 128 + d0 + db;
#pragma unroll
    for (int j = 0; j < 16; j += 4) {
      float4 v = *(const float4*)(np + j);
      xiL[(db + j + 0) * 128 + e] = (_Float16)v.x;
      xiL[(db + j + 1) * 128 + e] = (_Float16)v.y;
      xiL[(db + j + 2) * 128 + e] = (_Float16)v.z;
      xiL[(db + j + 3) * 128 + e] = (_Float16)v.w;
    }
  }
  // prologue: DMA tile 0 into Bs[0] (dest = wave-uniform base + lane*16, linear)
  {
    const _Float16* gsrc = BTf + (size_t)d0 * 16384 + w * 512 + l * 8;
    _Float16* ldst = &Bs[0][w * 512 + l * 8];
#pragma unroll
    for (int j = 0; j < 8; ++j) gload16(gsrc + j * 2048, ldst + j * 2048);
  }
  __syncthreads();  // drains DMA + makes xiL/scL visible
  // A fragments with BN3+relu (dt-invariant): rows e0 + wm*64 + mb*32 + lr
  half8 xf[2][8];
#pragma unroll
  for (int mb = 0; mb < 2; ++mb) {
    const float* xp = y3 + (size_t)(e0 + wm * 64 + mb * 32 + lr) * 128 + lg * 8;
#pragma unroll
    for (int ks = 0; ks < 8; ++ks) {
      const int c = ks * 16 + lg * 8;
      float4 a = *(const float4*)(xp + ks * 16);
      float4 b = *(const float4*)(xp + ks * 16 + 4);
      float va[8] = {a.x, a.y, a.z, a.w, b.x, b.y, b.z, b.w};
      half8 h;
#pragma unroll
      for (int j = 0; j < 8; ++j)
        h[j] = (_Float16)fmaxf(va[j] * scL[c + j] + shL[c + j], 0.f);
      xf[mb][ks] = h;
    }
  }
  f32x16 acc00 = (f32x16){0.f}, acc01 = (f32x16){0.f};
  f32x16 acc10 = (f32x16){0.f}, acc11 = (f32x16){0.f};

  for (int dt = 0; dt < 32; ++dt) {
    // wait own DMA for Bs[cur]; align all waves (their DMAs also waited)
    asm volatile("s_waitcnt vmcnt(0)" ::: "memory");
    __builtin_amdgcn_s_barrier();
    const _Float16* bs = &Bs[dt & 1][0];
    // issue next tile DMA AFTER barrier (prev readers of Bs[next] are done)
    if (dt < 31) {
      const _Float16* gsrc = BTf + (size_t)(d0 + dt + 1) * 16384 + w * 512 + l * 8;
      _Float16* ldst = &Bs[(dt + 1) & 1][w * 512 + l * 8];
#pragma unroll
      for (int j = 0; j < 8; ++j) gload16(gsrc + j * 2048, ldst + j * 2048);
    }
    const _Float16 xv0 = xiL[dt * 128 + wm * 64 + lr];
    const _Float16 xv1 = xiL[dt * 128 + wm * 64 + 32 + lr];
    const half8 xb0 = {xv0, xv0, xv0, xv0, xv0, xv0, xv0, xv0};
    const half8 xb1 = {xv1, xv1, xv1, xv1, xv1, xv1, xv1, xv1};
#pragma unroll
    for (int ks = 0; ks < 8; ++ks) {
      half8 b0 = *(const half8*)(bs + (size_t)(((wn * 2 + 0) * 8 + ks) * 64 + l) * 8);
      half8 b1 = *(const half8*)(bs + (size_t)(((wn * 2 + 1) * 8 + ks) * 64 + l) * 8);
      half8 a0 = xf[0][ks] * xb0;
      half8 a1 = xf[1][ks] * xb1;
      acc00 = __builtin_amdgcn_mfma_f32_32x32x16_f16(a0, b0, acc00, 0, 0, 0);
      acc01 = __builtin_amdgcn_mfma_f32_32x32x16_f16(a0, b1, acc01, 0, 0, 0);
      acc10 = __builtin_amdgcn_mfma_f32_32x32x16_f16(a1, b0, acc10, 0, 0, 0);
      acc11 = __builtin_amdgcn_mfma_f32_32x32x16_f16(a1, b1, acc11, 0, 0, 0);
    }
  }
  // epilogue: direct scatter into sums[dst]; split 0 adds Tn[src]
  const bool add_t = (blockIdx.x == 0);
#pragma unroll
  for (int r = 0; r < 16; ++r) {
    const int rl = (r & 3) + 8 * (r >> 2) + 4 * lg;
    const int eA = e0 + wm * 64 + rl;
    const int eB = eA + 32;
    const int dA = eidx[eA * 2 + 1], sA = eidx[eA * 2];
    const int dB = eidx[eB * 2 + 1], sB = eidx[eB * 2];
    const int c0 = wn * 64 + lr;
    float v00 = acc00[r], v01 = acc01[r], v10 = acc10[r], v11 = acc11[r];
    if (add_t) {
      v00 += Tn[(size_t)sA * 128 + c0];
      v01 += Tn[(size_t)sA * 128 + c0 + 32];
      v10 += Tn[(size_t)sB * 128 + c0];
      v11 += Tn[(size_t)sB * 128 + c0 + 32];
    }
    atomicAdd(&sums[(size_t)dA * 128 + c0], v00);
    atomicAdd(&sums[(size_t)dA * 128 + c0 + 32], v01);
    atomicAdd(&sums[(size_t)dB * 128 + c0], v10);
    atomicAdd(&sums[(size_t)dB * 128 + c0 + 32], v11);
  }
}

// ---------------- Tn = node @ t4mat  (+ fused edge-count) ----------------
__global__ __launch_bounds__(128) void t4n_kernel(const float* __restrict__ node,
                                                  const float* __restrict__ t4,
                                                  float* __restrict__ Tn,
                                                  const int* __restrict__ eidx,
                                                  float* __restrict__ cnt, int E) {
  __shared__ float nodeL[8][128];
  const int k = threadIdx.x;
  const int n0 = blockIdx.x * 8;
  {
    int e = blockIdx.x * 32 + k;
    if (k < 32 && e < E) atomicAdd(&cnt[eidx[e * 2 + 1]], 1.0f);
  }
#pragma unroll
  for (int j = 0; j < 8; ++j) nodeL[j][k] = node[(size_t)(n0 + j) * 128 + k];
  __syncthreads();
  float acc[8] = {};
  for (int d = 0; d < 128; ++d) {
    float wv = t4[d * 128 + k];
#pragma unroll
    for (int j = 0; j < 8; ++j) acc[j] += nodeL[j][d] * wv;
  }
#pragma unroll
  for (int j = 0; j < 8; ++j) Tn[(size_t)(n0 + j) * 128 + k] = acc[j];
}

// ---------------- GRU gates: bx<3 -> gi (mrelu A), else gh ----------------
__global__ __launch_bounds__(256) void gru_gates(const float* __restrict__ sums,
                                                 const float* __restrict__ cnt,
                                                 const float* __restrict__ bias,
                                                 const float* __restrict__ h0,
                                                 const float* __restrict__ Wih,
                                                 const float* __restrict__ Whh,
                                                 float* __restrict__ gi,
                                                 float* __restrict__ gh) {
  __shared__ _Float16 As[128 * 64];
  __shared__ _Float16 Bs[128 * 64];
  const bool isgh = blockIdx.x >= 3;
  const float* A = isgh ? h0 : sums;
  const float* B = isgh ? Whh : Wih;
  float* C = isgh ? gh : gi;
  const int n0 = (isgh ? blockIdx.x - 3 : blockIdx.x) * 128;
  const int m0 = blockIdx.y * 128;
  const int t = threadIdx.x;
  const int w = t >> 6, l = t & 63;
  const int wm = w >> 1, wn = w & 1;
  const int lr = l & 31, lg = l >> 5;
  f32x16 acc[2][2];
#pragma unroll
  for (int i = 0; i < 2; ++i)
#pragma unroll
    for (int j = 0; j < 2; ++j) acc[i][j] = (f32x16){0.f};
  for (int k0 = 0; k0 < 128; k0 += 64) {
    __syncthreads();
#pragma unroll
    for (int i = 0; i < 4; ++i) {
      const int gq = i * 256 + t;
      const int f = gq >> 6, lp = gq & 63;
      const int row = (f >> 2) * 32 + (lp & 31);
      const int c = (f & 3) * 16 + (lp >> 5) * 8;
      const float* ap = A + (size_t)(m0 + row) * 128 + k0 + c;
      float4 a4 = *(const float4*)ap, b4 = *(const float4*)(ap + 4);
      float va[8] = {a4.x, a4.y, a4.z, a4.w, b4.x, b4.y, b4.z, b4.w};
      if (!isgh) {
        float rc = 1.f / fmaxf(cnt[m0 + row], 1.f);
#pragma unroll
        for (int j = 0; j < 8; ++j) va[j] = fmaxf(va[j] * rc + bias[k0 + c + j], 0.f);
      }
      half8 h;
#pragma unroll
      for (int j = 0; j < 8; ++j) h[j] = (_Float16)va[j];
      *(half8*)(As + (size_t)gq * 8) = h;
      const float* bp = B + (size_t)(n0 + row) * 128 + k0 + c;
      float4 e4 = *(const float4*)bp, f4 = *(const float4*)(bp + 4);
      half8 hb;
      hb[0] = (_Float16)e4.x; hb[1] = (_Float16)e4.y; hb[2] = (_Float16)e4.z; hb[3] = (_Float16)e4.w;
      hb[4] = (_Float16)f4.x; hb[5] = (_Float16)f4.y; hb[6] = (_Float16)f4.z; hb[7] = (_Float16)f4.w;
      *(half8*)(Bs + (size_t)gq * 8) = hb;
    }
    __syncthreads();
#pragma unroll
    for (int ks = 0; ks < 4; ++ks) {
      half8 af[2], bf[2];
#pragma unroll
      for (int mb = 0; mb < 2; ++mb) {
        af[mb] = *(const half8*)(As + (size_t)(((wm * 2 + mb) * 4 + ks) * 64 + l) * 8);
        bf[mb] = *(const half8*)(Bs + (size_t)(((wn * 2 + mb) * 4 + ks) * 64 + l) * 8);
      }
#pragma unroll
      for (int mb = 0; mb < 2; ++mb)
#pragma unroll
        for (int nb = 0; nb < 2; ++nb)
          acc[mb][nb] = __builtin_amdgcn_mfma_f32_32x32x16_f16(af[mb], bf[nb], acc[mb][nb], 0, 0, 0);
    }
  }
#pragma unroll
  for (int mb = 0; mb < 2; ++mb)
#pragma unroll
    for (int nb = 0; nb < 2; ++nb)
#pragma unroll
      for (int r = 0; r < 16; ++r) {
        const int row = m0 + wm * 64 + mb * 32 + (r & 3) + 8 * (r >> 2) + 4 * lg;
        const int col = n0 + wn * 64 + nb * 32 + lr;
        C[(size_t)row * 384 + col] = acc[mb][nb][r];
      }
}

// ---------------- GRU finalize ----------------
__global__ __launch_bounds__(256) void gru_finalize(const float* __restrict__ gi,
                                                    const float* __restrict__ gh,
                                                    const float* __restrict__ h0,
                                                    const float* __restrict__ bih,
                                                    const float* __restrict__ bhh,
                                                    float* __restrict__ out, int Nn) {
  int idx = blockIdx.x * 256 + threadIdx.x;
  int n = idx >> 7, k = idx & 127;
  const float* gin = gi + (size_t)n * 384;
  const float* ghn = gh + (size_t)n * 384;
  float r = 1.f / (1.f + expf(-(gin[k] + bih[k] + ghn[k] + bhh[k])));
  float z = 1.f / (1.f + expf(-(gin[128 + k] + bih[128 + k] + ghn[128 + k] + bhh[128 + k])));
  float nn = tanhf(gin[256 + k] + bih[256 + k] + r * (ghn[256 + k] + bhh[256 + k]));
  float h = h0[idx];
  float hn = (1.f - z) * nn + z * h;
  out[idx] = hn;
  out[idx + (size_t)Nn * 128] = hn;
}

extern "C" void kernel_launch(void* const* d_in, const int* in_sizes, int n_in,
                              void* d_out, int out_size, void* d_ws, size_t ws_size,
                              hipStream_t stream) {
  const float* node = (const float*)d_in[0];
  const int* eidx = (const int*)d_in[1];
  const float* edge = (const float*)d_in[2];
  const float* hidden = (const float*)d_in[3];
  const float* W1 = (const float*)d_in[4];
  const float* g1 = (const float*)d_in[5];
  const float* b1 = (const float*)d_in[6];
  const float* W2 = (const float*)d_in[7];
  const float* g2 = (const float*)d_in[8];
  const float* b2 = (const float*)d_in[9];
  const float* W3 = (const float*)d_in[10];
  const float* g3 = (const float*)d_in[11];
  const float* b3 = (const float*)d_in[12];
  const float* W4 = (const float*)d_in[13];
  const float* g4 = (const float*)d_in[14];
  const float* b4 = (const float*)d_in[15];
  const float* bias = (const float*)d_in[16];
  const float* Wih = (const float*)d_in[17];
  const float* Whh = (const float*)d_in[18];
  const float* bih = (const float*)d_in[19];
  const float* bhh = (const float*)d_in[20];
  float* out = (float*)d_out;

  const int Nn = in_sizes[0] / 128;   // 4096
  const int E = in_sizes[2] / 16;     // 16384
  const float invE = 1.0f / (float)E;

  float* ws = (float*)d_ws;
  float* ybuf1 = ws + 0;                       // E x 256 (y1 raw) -> gram partials 128x16384
  float* ybuf2 = ws + 4194304;                 // E x 256 (y2 raw) -> U -> gi/gh
  float* y3buf = ws + 8388608;                 // E x 128 (y3 RAW, BN3 fused in consumers)
  _Float16* BTf = (_Float16*)(ws + 10485760);  // 128 tiles x 16384 halves (4MB)
  float* t4 = ws + 11534336;                   // 16384
  float* stats = ws + 11550720;                // stat1,stat2,stat3 (3x512) + colsum3 (128)
  float* G3 = ws + 11552512;                   // 16384
  float* sums = ws + 11568896;                 // Nn x 128
  float* cnt = ws + 12093184;                  // Nn
  float* Tn = ws + 12097280;                   // Nn x 128
  float* stat1 = stats, *stat2 = stats + 512, *stat3 = stats + 1024;
  float* colsum3 = stats + 1536;
  float* gpart = ybuf1;                        // 128 x 16384
  float* U = ybuf2;                            // 16384 x 128
  float* gi = ybuf2;                           // 4096 x 384
  float* gh = ybuf2 + 1572864;                 // 4096 x 384

  hipMemsetAsync(stats, 0, 1664 * sizeof(float), stream);
  hipMemsetAsync(sums, 0, ((size_t)Nn * 128 + Nn) * sizeof(float), stream);

  // L1: y1 = edge @ W1^T (+stats1)
  gemm_abt<<<dim3(4, E / 64), 256, 0, stream>>>(edge, W1, ybuf1, E, 256, 16, stat1, stat1 + 256);
  // L2: y2 = bn1relu(y1) @ W2^T (+stats2)
  gemm16<1, true><<<dim3(2, E / 128), 256, 0, stream>>>(ybuf1, W2, ybuf2, 256, 256, 256, 256,
                                                        stat1, stat1 + 256, g1, b1, invE,
                                                        stat2, stat2 + 256);
  // L3: y3 = bn2relu(y2) @ W3^T (+stats3)
  gemm16<1, true><<<dim3(1, E / 128), 256, 0, stream>>>(ybuf2, W3, y3buf, 256, 256, 128, 256,
                                                        stat2, stat2 + 256, g2, b2, invE,
                                                        stat3, stat3 + 256);

  // Gram on bn3relu(y3) (fused) -> partials + colsum3 -> reduce
  gram_kernel<<<E / 128, 256, 0, stream>>>(y3buf, gpart, stat3, stat3 + 256, g3, b3, invE,
                                           colsum3);
  gram_reduce<<<64, 256, 0, stream>>>(gpart, G3);

  // U = W4 @ G3
  gemm16<0, false><<<dim3(1, 16384 / 128), 256, 0, stream>>>(W4, G3, U, 128, 128, 128, 128,
                                                             nullptr, nullptr, nullptr, nullptr,
                                                             0.f, nullptr, nullptr);
  w4_finalize<<<16384 / 4, 256, 0, stream>>>(W4, U, colsum3, g4, b4, BTf, t4, invE);
  t4n_kernel<<<Nn / 8, 128, 0, stream>>>(node, t4, Tn, eidx, cnt, E);

  // fused message GEMM with DMA-staged B and direct scatter
  zgemm<<<dim3(4, E / 128), 256, 0, stream>>>(y3buf, node, eidx, BTf, Tn,
                                              stat3, stat3 + 256, g3, b3, invE, sums);

  // GRU
  gru_gates<<<dim3(6, Nn / 128), 256, 0, stream>>>(sums, cnt, bias, hidden, Wih, Whh, gi, gh);
  gru_finalize<<<Nn * 128 / 256, 256, 0, stream>>>(gi, gh, hidden, bih, bhh, out, Nn);
}

// Round 11
// 239.872 us; speedup vs baseline: 1.2098x; 1.0707x over previous
//
#include <hip/hip_runtime.h>

#define EPS 1e-5f

typedef _Float16 half8 __attribute__((ext_vector_type(8)));
typedef _Float16 half4 __attribute__((ext_vector_type(4)));
typedef float f32x16 __attribute__((ext_vector_type(16)));

// ---------------- L1: C(half) = A(Mx16) @ B(Nx16)^T, + col-stats epilogue ----------------
__global__ __launch_bounds__(256) void gemm_abt(const float* __restrict__ A,
                                                const float* __restrict__ B,
                                                _Float16* __restrict__ C,
                                                int M, int N, int K,
                                                float* __restrict__ osum,
                                                float* __restrict__ osq) {
  __shared__ float As[16][68];
  __shared__ float Bs[16][68];
  const int t = threadIdx.x;
  const int tx = t & 15, ty = t >> 4;
  const int m0 = blockIdx.y * 64, n0 = blockIdx.x * 64;
  float acc[4][4] = {};
  for (int k0 = 0; k0 < K; k0 += 16) {
    __syncthreads();
    {
      const int r = t >> 2;
      const int kk = (t & 3) << 2;
      float4 av = *(const float4*)&A[(size_t)(m0 + r) * K + k0 + kk];
      As[kk + 0][r] = av.x; As[kk + 1][r] = av.y;
      As[kk + 2][r] = av.z; As[kk + 3][r] = av.w;
      float4 bv = *(const float4*)&B[(size_t)(n0 + r) * K + k0 + kk];
      Bs[kk + 0][r] = bv.x; Bs[kk + 1][r] = bv.y;
      Bs[kk + 2][r] = bv.z; Bs[kk + 3][r] = bv.w;
    }
    __syncthreads();
#pragma unroll
    for (int kk = 0; kk < 16; ++kk) {
      float4 a = *(const float4*)&As[kk][ty << 2];
      float4 b = *(const float4*)&Bs[kk][tx << 2];
      float av[4] = {a.x, a.y, a.z, a.w};
      float bv[4] = {b.x, b.y, b.z, b.w};
#pragma unroll
      for (int i = 0; i < 4; ++i)
#pragma unroll
        for (int j = 0; j < 4; ++j) acc[i][j] += av[i] * bv[j];
    }
  }
#pragma unroll
  for (int i = 0; i < 4; ++i) {
    half4 o;
    o[0] = (_Float16)acc[i][0]; o[1] = (_Float16)acc[i][1];
    o[2] = (_Float16)acc[i][2]; o[3] = (_Float16)acc[i][3];
    *(half4*)&C[(size_t)(m0 + (ty << 2) + i) * N + n0 + (tx << 2)] = o;
  }
  __syncthreads();
  float* sred = (float*)As;
  if (t < 128) sred[t] = 0.f;
  __syncthreads();
#pragma unroll
  for (int j = 0; j < 4; ++j) {
    float s = 0.f, sq = 0.f;
#pragma unroll
    for (int i = 0; i < 4; ++i) {
      float v = acc[i][j];
      s += v; sq += v * v;
    }
    atomicAdd(&sred[((tx << 2) + j) * 2 + 0], s);
    atomicAdd(&sred[((tx << 2) + j) * 2 + 1], sq);
  }
  __syncthreads();
  if (t < 64) {
    atomicAdd(&osum[n0 + t], sred[t * 2]);
    atomicAdd(&osq[n0 + t], sred[t * 2 + 1]);
  }
}

// ---------------- MFMA fp16 GEMM: C = T(A) @ B^T ; AH/CH select fp16 A/C ----------------
template <int TRANS, bool STATS, bool AH, bool CH>
__global__ __launch_bounds__(256) void gemm16(const void* __restrict__ Ap,
                                              const float* __restrict__ B,
                                              void* __restrict__ Cp,
                                              int lda, int ldb, int ldc, int K,
                                              const float* __restrict__ s1,
                                              const float* __restrict__ s2,
                                              const float* __restrict__ g,
                                              const float* __restrict__ b,
                                              float invM,
                                              float* __restrict__ osum,
                                              float* __restrict__ osq) {
  __shared__ _Float16 As[128 * 64];
  __shared__ _Float16 Bs[128 * 64];
  __shared__ float scL[256], shL[256];
  const int t = threadIdx.x;
  const int m0 = blockIdx.y * 128, n0 = blockIdx.x * 128;
  const int w = t >> 6, l = t & 63;
  const int wm = w >> 1, wn = w & 1;
  const int lr = l & 31, lg = l >> 5;
  if (TRANS == 1) {
    if (t < K) {
      float mean = s1[t] * invM;
      float var = s2[t] * invM - mean * mean;
      float sc = g[t] * rsqrtf(var + EPS);
      scL[t] = sc;
      shL[t] = b[t] - mean * sc;
    }
  }
  f32x16 acc[2][2];
#pragma unroll
  for (int i = 0; i < 2; ++i)
#pragma unroll
    for (int j = 0; j < 2; ++j) acc[i][j] = (f32x16){0.f};
  for (int k0 = 0; k0 < K; k0 += 64) {
    __syncthreads();
#pragma unroll
    for (int i = 0; i < 4; ++i) {
      const int gq = i * 256 + t;
      const int f = gq >> 6, lp = gq & 63;
      const int row = (f >> 2) * 32 + (lp & 31);
      const int c = (f & 3) * 16 + (lp >> 5) * 8;
      float va[8];
      if (AH) {
        const _Float16* ap = (const _Float16*)Ap + (size_t)(m0 + row) * lda + k0 + c;
        half8 av = *(const half8*)ap;
#pragma unroll
        for (int j = 0; j < 8; ++j) va[j] = (float)av[j];
      } else {
        const float* ap = (const float*)Ap + (size_t)(m0 + row) * lda + k0 + c;
        float4 a4 = *(const float4*)ap, b4 = *(const float4*)(ap + 4);
        va[0] = a4.x; va[1] = a4.y; va[2] = a4.z; va[3] = a4.w;
        va[4] = b4.x; va[5] = b4.y; va[6] = b4.z; va[7] = b4.w;
      }
      if (TRANS == 1) {
#pragma unroll
        for (int j = 0; j < 8; ++j)
          va[j] = fmaxf(va[j] * scL[k0 + c + j] + shL[k0 + c + j], 0.f);
      }
      half8 h;
#pragma unroll
      for (int j = 0; j < 8; ++j) h[j] = (_Float16)va[j];
      *(half8*)(As + (size_t)gq * 8) = h;
      const float* bp = B + (size_t)(n0 + row) * ldb + k0 + c;
      float4 e4 = *(const float4*)bp, f4 = *(const float4*)(bp + 4);
      half8 hb;
      hb[0] = (_Float16)e4.x; hb[1] = (_Float16)e4.y; hb[2] = (_Float16)e4.z; hb[3] = (_Float16)e4.w;
      hb[4] = (_Float16)f4.x; hb[5] = (_Float16)f4.y; hb[6] = (_Float16)f4.z; hb[7] = (_Float16)f4.w;
      *(half8*)(Bs + (size_t)gq * 8) = hb;
    }
    __syncthreads();
#pragma unroll
    for (int ks = 0; ks < 4; ++ks) {
      half8 af[2], bf[2];
#pragma unroll
      for (int mb = 0; mb < 2; ++mb) {
        af[mb] = *(const half8*)(As + (size_t)(((wm * 2 + mb) * 4 + ks) * 64 + l) * 8);
        bf[mb] = *(const half8*)(Bs + (size_t)(((wn * 2 + mb) * 4 + ks) * 64 + l) * 8);
      }
#pragma unroll
      for (int mb = 0; mb < 2; ++mb)
#pragma unroll
        for (int nb = 0; nb < 2; ++nb)
          acc[mb][nb] = __builtin_amdgcn_mfma_f32_32x32x16_f16(af[mb], bf[nb], acc[mb][nb], 0, 0, 0);
    }
  }
#pragma unroll
  for (int mb = 0; mb < 2; ++mb)
#pragma unroll
    for (int nb = 0; nb < 2; ++nb)
#pragma unroll
      for (int r = 0; r < 16; ++r) {
        const int row = m0 + wm * 64 + mb * 32 + (r & 3) + 8 * (r >> 2) + 4 * lg;
        const int col = n0 + wn * 64 + nb * 32 + lr;
        if (CH) ((_Float16*)Cp)[(size_t)row * ldc + col] = (_Float16)acc[mb][nb][r];
        else ((float*)Cp)[(size_t)row * ldc + col] = acc[mb][nb][r];
      }
  if (STATS) {
    __syncthreads();
    float* sred = (float*)As;
    if (t < 256) sred[t] = 0.f;
    __syncthreads();
#pragma unroll
    for (int nb = 0; nb < 2; ++nb) {
      float s = 0.f, sq = 0.f;
#pragma unroll
      for (int mb = 0; mb < 2; ++mb)
#pragma unroll
        for (int r = 0; r < 16; ++r) {
          float v = acc[mb][nb][r];
          s += v; sq += v * v;
        }
      const int cl = wn * 64 + nb * 32 + lr;
      atomicAdd(&sred[cl * 2 + 0], s);
      atomicAdd(&sred[cl * 2 + 1], sq);
    }
    __syncthreads();
    if (t < 128) {
      atomicAdd(&osum[n0 + t], sred[t * 2]);
      atomicAdd(&osq[n0 + t], sred[t * 2 + 1]);
    }
  }
}

// ---------------- Gram partials on BN3(relu(y3h)): 128 blocks x 128 rows ----------------
__global__ __launch_bounds__(256) void gram_kernel(const _Float16* __restrict__ y3,
                                                   float* __restrict__ part,
                                                   const float* __restrict__ s3sum,
                                                   const float* __restrict__ s3sq,
                                                   const float* __restrict__ g3,
                                                   const float* __restrict__ b3,
                                                   float invE,
                                                   float* __restrict__ colsum) {
  __shared__ float xL[128 * 132];
  __shared__ float scL[128], shL[128];
  const int t = threadIdx.x, tx = t & 15, ty = t >> 4;
  if (t < 128) {
    float mean = s3sum[t] * invE;
    float var = s3sq[t] * invE - mean * mean;
    float sc = g3[t] * rsqrtf(var + EPS);
    scL[t] = sc;
    shL[t] = b3[t] - mean * sc;
  }
  __syncthreads();
  const int r0 = blockIdx.x * 128;
#pragma unroll
  for (int i = 0; i < 16; ++i) {
    int f4 = t + i * 256;
    int r = f4 >> 5;
    int c4 = (f4 & 31) << 2;
    half4 hv = *(const half4*)&y3[(size_t)(r0 + r) * 128 + c4];
    float4 v;
    v.x = fmaxf((float)hv[0] * scL[c4 + 0] + shL[c4 + 0], 0.f);
    v.y = fmaxf((float)hv[1] * scL[c4 + 1] + shL[c4 + 1], 0.f);
    v.z = fmaxf((float)hv[2] * scL[c4 + 2] + shL[c4 + 2], 0.f);
    v.w = fmaxf((float)hv[3] * scL[c4 + 3] + shL[c4 + 3], 0.f);
    *(float4*)&xL[r * 132 + c4] = v;
  }
  __syncthreads();
  float acc[8][8] = {};
  float csum[8] = {};
  for (int r = 0; r < 128; ++r) {
    float4 a0 = *(const float4*)&xL[r * 132 + ty * 8];
    float4 a1 = *(const float4*)&xL[r * 132 + ty * 8 + 4];
    float4 b0 = *(const float4*)&xL[r * 132 + tx * 8];
    float4 b1 = *(const float4*)&xL[r * 132 + tx * 8 + 4];
    float a[8] = {a0.x, a0.y, a0.z, a0.w, a1.x, a1.y, a1.z, a1.w};
    float b[8] = {b0.x, b0.y, b0.z, b0.w, b1.x, b1.y, b1.z, b1.w};
#pragma unroll
    for (int i = 0; i < 8; ++i)
#pragma unroll
      for (int j = 0; j < 8; ++j) acc[i][j] += a[i] * b[j];
    if (tx == ty) {
#pragma unroll
      for (int i = 0; i < 8; ++i) csum[i] += a[i];
    }
  }
  float* base = part + (size_t)blockIdx.x * 16384;
#pragma unroll
  for (int i = 0; i < 8; ++i)
#pragma unroll
    for (int j = 0; j < 8; ++j)
      base[(ty * 8 + i) * 128 + tx * 8 + j] = acc[i][j];
  if (tx == ty) {
#pragma unroll
    for (int i = 0; i < 8; ++i) atomicAdd(&colsum[ty * 8 + i], csum[i]);
  }
}

__global__ __launch_bounds__(256) void gram_reduce(const float* __restrict__ part,
                                                   float* __restrict__ out) {
  int idx = blockIdx.x * 256 + threadIdx.x;
  float s = 0.f;
  for (int b = 0; b < 128; ++b) s += part[(size_t)b * 16384 + idx];
  out[idx] = s;
}

// ---------------- finalize layer-4 BN; emit BTf (fp16 fragment-major) + t4 ----------------
__global__ __launch_bounds__(256) void w4_finalize(const float* __restrict__ W4,
                                                   const float* __restrict__ U,
                                                   const float* __restrict__ colsum3,
                                                   const float* __restrict__ g4,
                                                   const float* __restrict__ b4,
                                                   _Float16* __restrict__ BTf,
                                                   float* __restrict__ t4,
                                                   float invM) {
  const int r = (blockIdx.x * 256 + threadIdx.x) >> 6;
  const int lane = threadIdx.x & 63;
  const float* wp = W4 + (size_t)r * 128;
  const float* up = U + (size_t)r * 128;
  float p1 = 0.f, p2 = 0.f;
#pragma unroll
  for (int c0 = 0; c0 < 128; c0 += 64) {
    float wv = wp[c0 + lane];
    p1 += up[c0 + lane] * wv;
    p2 += colsum3[c0 + lane] * wv;
  }
#pragma unroll
  for (int off = 32; off > 0; off >>= 1) {
    p1 += __shfl_down(p1, off);
    p2 += __shfl_down(p2, off);
  }
  p1 = __shfl(p1, 0);
  p2 = __shfl(p2, 0);
  float m4 = p2 * invM;
  float q = p1 * invM;
  float s = g4[r] * rsqrtf(q - m4 * m4 + EPS);
  if (lane == 0) t4[r] = b4[r] - m4 * s;
  const int kout = r & 127, d = r >> 7;
  if (lane < 16) {
    const int ks = lane >> 1, lg = lane & 1;
    const float* cp = wp + lane * 8;
    float4 va = *(const float4*)cp, vb = *(const float4*)(cp + 4);
    half8 h;
    h[0] = (_Float16)(s * va.x); h[1] = (_Float16)(s * va.y);
    h[2] = (_Float16)(s * va.z); h[3] = (_Float16)(s * va.w);
    h[4] = (_Float16)(s * vb.x); h[5] = (_Float16)(s * vb.y);
    h[6] = (_Float16)(s * vb.z); h[7] = (_Float16)(s * vb.w);
    size_t off16 = (size_t)d * 16384 +
                   (size_t)((((kout >> 5) * 8 + ks) * 64) + (kout & 31) + lg * 32) * 8;
    *(half8*)(BTf + off16) = h;
  }
}

// ---------------- zgemm: R8 layout + write-ahead pipeline ----------------
// 2x2 waves of 64e x 64n, tile 128e x 128n, KSPLIT=4 -> grid (4, E/128), 2 blocks/CU.
// Bs[cur] written one iteration early; per dt: {ds_read ∥ ds_write(next) ∥ gload(dt+2)}
// -> MFMA -> lgkmcnt(0)+s_barrier (global prefetch stays in flight).
__global__ __launch_bounds__(256, 2) void zgemm(const _Float16* __restrict__ y3,
                                                const float* __restrict__ node,
                                                const int* __restrict__ eidx,
                                                const _Float16* __restrict__ BTf,
                                                const float* __restrict__ Tn,
                                                const float* __restrict__ s3sum,
                                                const float* __restrict__ s3sq,
                                                const float* __restrict__ g3,
                                                const float* __restrict__ b3,
                                                float invE,
                                                float* __restrict__ sums) {
  __shared__ __align__(16) _Float16 Bs[2][16384];  // 2 x 32KB fragment-major
  __shared__ _Float16 xiL[32 * 128];               // [d][e] 8KB
  __shared__ float scL[128], shL[128];
  const int t = threadIdx.x;
  const int e0 = blockIdx.y * 128;
  const int d0 = blockIdx.x * 32;
  const int w = t >> 6, l = t & 63;
  const int wm = w >> 1, wn = w & 1;
  const int lr = l & 31, lg = l >> 5;
  // BN3 scale/shift table
  if (t < 128) {
    float mean = s3sum[t] * invE;
    float var = s3sq[t] * invE - mean * mean;
    float sc = g3[t] * rsqrtf(var + EPS);
    scL[t] = sc;
    shL[t] = b3[t] - mean * sc;
  }
  // stage xiL[d][e]
  {
    const int e = t >> 1, db = (t & 1) * 16;
    const int src = eidx[(e0 + e) * 2];
    const float* np = node + (size_t)src * 128 + d0 + db;
#pragma unroll
    for (int j = 0; j < 16; j += 4) {
      float4 v = *(const float4*)(np + j);
      xiL[(db + j + 0) * 128 + e] = (_Float16)v.x;
      xiL[(db + j + 1) * 128 + e] = (_Float16)v.y;
      xiL[(db + j + 2) * 128 + e] = (_Float16)v.z;
      xiL[(db + j + 3) * 128 + e] = (_Float16)v.w;
    }
  }
  // prologue: tile0 -> regs -> Bs[0]; tile1 -> regs
  half8 st[8];
  {
    const _Float16* p = BTf + (size_t)d0 * 16384 + (size_t)t * 8;
#pragma unroll
    for (int j = 0; j < 8; ++j) st[j] = *(const half8*)(p + j * 2048);
  }
#pragma unroll
  for (int j = 0; j < 8; ++j) *(half8*)(&Bs[0][0] + t * 8 + j * 2048) = st[j];
  {
    const _Float16* p = BTf + (size_t)(d0 + 1) * 16384 + (size_t)t * 8;
#pragma unroll
    for (int j = 0; j < 8; ++j) st[j] = *(const half8*)(p + j * 2048);
  }
  __syncthreads();  // Bs[0] + xiL/scL visible
  // A fragments with BN3+relu (dt-invariant): rows e0 + wm*64 + mb*32 + lr
  half8 xf[2][8];
#pragma unroll
  for (int mb = 0; mb < 2; ++mb) {
    const _Float16* xp = y3 + (size_t)(e0 + wm * 64 + mb * 32 + lr) * 128 + lg * 8;
#pragma unroll
    for (int ks = 0; ks < 8; ++ks) {
      const int c = ks * 16 + lg * 8;
      half8 hv = *(const half8*)(xp + ks * 16);
      half8 h;
#pragma unroll
      for (int j = 0; j < 8; ++j)
        h[j] = (_Float16)fmaxf((float)hv[j] * scL[c + j] + shL[c + j], 0.f);
      xf[mb][ks] = h;
    }
  }
  f32x16 acc00 = (f32x16){0.f}, acc01 = (f32x16){0.f};
  f32x16 acc10 = (f32x16){0.f}, acc11 = (f32x16){0.f};

  for (int dt = 0; dt < 32; ++dt) {
    const _Float16* bs = &Bs[dt & 1][0];
    _Float16* bsn = &Bs[(dt + 1) & 1][0];
    const _Float16 xv0 = xiL[dt * 128 + wm * 64 + lr];
    const _Float16 xv1 = xiL[dt * 128 + wm * 64 + 32 + lr];
    const half8 xb0 = {xv0, xv0, xv0, xv0, xv0, xv0, xv0, xv0};
    const half8 xb1 = {xv1, xv1, xv1, xv1, xv1, xv1, xv1, xv1};
    __builtin_amdgcn_s_setprio(1);
#pragma unroll
    for (int ks = 0; ks < 8; ++ks) {
      half8 b0 = *(const half8*)(bs + (size_t)(((wn * 2 + 0) * 8 + ks) * 64 + l) * 8);
      half8 b1 = *(const half8*)(bs + (size_t)(((wn * 2 + 1) * 8 + ks) * 64 + l) * 8);
      if (dt < 31) *(half8*)(bsn + t * 8 + ks * 2048) = st[ks];  // write NEXT tile under MFMA
      half8 a0 = xf[0][ks] * xb0;
      half8 a1 = xf[1][ks] * xb1;
      acc00 = __builtin_amdgcn_mfma_f32_32x32x16_f16(a0, b0, acc00, 0, 0, 0);
      acc01 = __builtin_amdgcn_mfma_f32_32x32x16_f16(a0, b1, acc01, 0, 0, 0);
      acc10 = __builtin_amdgcn_mfma_f32_32x32x16_f16(a1, b0, acc10, 0, 0, 0);
      acc11 = __builtin_amdgcn_mfma_f32_32x32x16_f16(a1, b1, acc11, 0, 0, 0);
    }
    __builtin_amdgcn_s_setprio(0);
    if (dt < 30) {  // prefetch tile dt+2 into st (st's tile dt+1 consumed above)
      const _Float16* p = BTf + (size_t)(d0 + dt + 2) * 16384 + (size_t)t * 8;
#pragma unroll
      for (int j = 0; j < 8; ++j) st[j] = *(const half8*)(p + j * 2048);
    }
    asm volatile("s_waitcnt lgkmcnt(0)" ::: "memory");  // ds_writes (drained under MFMA)
    __builtin_amdgcn_s_barrier();                        // global loads stay in flight
  }
  // epilogue: direct scatter into sums[dst]; split 0 adds Tn[src]
  const bool add_t = (blockIdx.x == 0);
#pragma unroll
  for (int r = 0; r < 16; ++r) {
    const int rl = (r & 3) + 8 * (r >> 2) + 4 * lg;
    const int eA = e0 + wm * 64 + rl;
    const int eB = eA + 32;
    const int dA = eidx[eA * 2 + 1], sA = eidx[eA * 2];
    const int dB = eidx[eB * 2 + 1], sB = eidx[eB * 2];
    const int c0 = wn * 64 + lr;
    float v00 = acc00[r], v01 = acc01[r], v10 = acc10[r], v11 = acc11[r];
    if (add_t) {
      v00 += Tn[(size_t)sA * 128 + c0];
      v01 += Tn[(size_t)sA * 128 + c0 + 32];
      v10 += Tn[(size_t)sB * 128 + c0];
      v11 += Tn[(size_t)sB * 128 + c0 + 32];
    }
    atomicAdd(&sums[(size_t)dA * 128 + c0], v00);
    atomicAdd(&sums[(size_t)dA * 128 + c0 + 32], v01);
    atomicAdd(&sums[(size_t)dB * 128 + c0], v10);
    atomicAdd(&sums[(size_t)dB * 128 + c0 + 32], v11);
  }
}

// ---------------- Tn = node @ t4mat  (+ fused edge-count) ----------------
__global__ __launch_bounds__(128) void t4n_kernel(const float* __restrict__ node,
                                                  const float* __restrict__ t4,
                                                  float* __restrict__ Tn,
                                                  const int* __restrict__ eidx,
                                                  float* __restrict__ cnt, int E) {
  __shared__ float nodeL[8][128];
  const int k = threadIdx.x;
  const int n0 = blockIdx.x * 8;
  {
    int e = blockIdx.x * 32 + k;
    if (k < 32 && e < E) atomicAdd(&cnt[eidx[e * 2 + 1]], 1.0f);
  }
#pragma unroll
  for (int j = 0; j < 8; ++j) nodeL[j][k] = node[(size_t)(n0 + j) * 128 + k];
  __syncthreads();
  float acc[8] = {};
  for (int d = 0; d < 128; ++d) {
    float wv = t4[d * 128 + k];
#pragma unroll
    for (int j = 0; j < 8; ++j) acc[j] += nodeL[j][d] * wv;
  }
#pragma unroll
  for (int j = 0; j < 8; ++j) Tn[(size_t)(n0 + j) * 128 + k] = acc[j];
}

// ---------------- GRU gates: bx<3 -> gi (mrelu A), else gh ----------------
__global__ __launch_bounds__(256) void gru_gates(const float* __restrict__ sums,
                                                 const float* __restrict__ cnt,
                                                 const float* __restrict__ bias,
                                                 const float* __restrict__ h0,
                                                 const float* __restrict__ Wih,
                                                 const float* __restrict__ Whh,
                                                 float* __restrict__ gi,
                                                 float* __restrict__ gh) {
  __shared__ _Float16 As[128 * 64];
  __shared__ _Float16 Bs[128 * 64];
  const bool isgh = blockIdx.x >= 3;
  const float* A = isgh ? h0 : sums;
  const float* B = isgh ? Whh : Wih;
  float* C = isgh ? gh : gi;
  const int n0 = (isgh ? blockIdx.x - 3 : blockIdx.x) * 128;
  const int m0 = blockIdx.y * 128;
  const int t = threadIdx.x;
  const int w = t >> 6, l = t & 63;
  const int wm = w >> 1, wn = w & 1;
  const int lr = l & 31, lg = l >> 5;
  f32x16 acc[2][2];
#pragma unroll
  for (int i = 0; i < 2; ++i)
#pragma unroll
    for (int j = 0; j < 2; ++j) acc[i][j] = (f32x16){0.f};
  for (int k0 = 0; k0 < 128; k0 += 64) {
    __syncthreads();
#pragma unroll
    for (int i = 0; i < 4; ++i) {
      const int gq = i * 256 + t;
      const int f = gq >> 6, lp = gq & 63;
      const int row = (f >> 2) * 32 + (lp & 31);
      const int c = (f & 3) * 16 + (lp >> 5) * 8;
      const float* ap = A + (size_t)(m0 + row) * 128 + k0 + c;
      float4 a4 = *(const float4*)ap, b4 = *(const float4*)(ap + 4);
      float va[8] = {a4.x, a4.y, a4.z, a4.w, b4.x, b4.y, b4.z, b4.w};
      if (!isgh) {
        float rc = 1.f / fmaxf(cnt[m0 + row], 1.f);
#pragma unroll
        for (int j = 0; j < 8; ++j) va[j] = fmaxf(va[j] * rc + bias[k0 + c + j], 0.f);
      }
      half8 h;
#pragma unroll
      for (int j = 0; j < 8; ++j) h[j] = (_Float16)va[j];
      *(half8*)(As + (size_t)gq * 8) = h;
      const float* bp = B + (size_t)(n0 + row) * 128 + k0 + c;
      float4 e4 = *(const float4*)bp, f4 = *(const float4*)(bp + 4);
      half8 hb;
      hb[0] = (_Float16)e4.x; hb[1] = (_Float16)e4.y; hb[2] = (_Float16)e4.z; hb[3] = (_Float16)e4.w;
      hb[4] = (_Float16)f4.x; hb[5] = (_Float16)f4.y; hb[6] = (_Float16)f4.z; hb[7] = (_Float16)f4.w;
      *(half8*)(Bs + (size_t)gq * 8) = hb;
    }
    __syncthreads();
#pragma unroll
    for (int ks = 0; ks < 4; ++ks) {
      half8 af[2], bf[2];
#pragma unroll
      for (int mb = 0; mb < 2; ++mb) {
        af[mb] = *(const half8*)(As + (size_t)(((wm * 2 + mb) * 4 + ks) * 64 + l) * 8);
        bf[mb] = *(const half8*)(Bs + (size_t)(((wn * 2 + mb) * 4 + ks) * 64 + l) * 8);
      }
#pragma unroll
      for (int mb = 0; mb < 2; ++mb)
#pragma unroll
        for (int nb = 0; nb < 2; ++nb)
          acc[mb][nb] = __builtin_amdgcn_mfma_f32_32x32x16_f16(af[mb], bf[nb], acc[mb][nb], 0, 0, 0);
    }
  }
#pragma unroll
  for (int mb = 0; mb < 2; ++mb)
#pragma unroll
    for (int nb = 0; nb < 2; ++nb)
#pragma unroll
      for (int r = 0; r < 16; ++r) {
        const int row = m0 + wm * 64 + mb * 32 + (r & 3) + 8 * (r >> 2) + 4 * lg;
        const int col = n0 + wn * 64 + nb * 32 + lr;
        C[(size_t)row * 384 + col] = acc[mb][nb][r];
      }
}

// ---------------- GRU finalize ----------------
__global__ __launch_bounds__(256) void gru_finalize(const float* __restrict__ gi,
                                                    const float* __restrict__ gh,
                                                    const float* __restrict__ h0,
                                                    const float* __restrict__ bih,
                                                    const float* __restrict__ bhh,
                                                    float* __restrict__ out, int Nn) {
  int idx = blockIdx.x * 256 + threadIdx.x;
  int n = idx >> 7, k = idx & 127;
  const float* gin = gi + (size_t)n * 384;
  const float* ghn = gh + (size_t)n * 384;
  float r = 1.f / (1.f + expf(-(gin[k] + bih[k] + ghn[k] + bhh[k])));
  float z = 1.f / (1.f + expf(-(gin[128 + k] + bih[128 + k] + ghn[128 + k] + bhh[128 + k])));
  float nn = tanhf(gin[256 + k] + bih[256 + k] + r * (ghn[256 + k] + bhh[256 + k]));
  float h = h0[idx];
  float hn = (1.f - z) * nn + z * h;
  out[idx] = hn;
  out[idx + (size_t)Nn * 128] = hn;
}

extern "C" void kernel_launch(void* const* d_in, const int* in_sizes, int n_in,
                              void* d_out, int out_size, void* d_ws, size_t ws_size,
                              hipStream_t stream) {
  const float* node = (const float*)d_in[0];
  const int* eidx = (const int*)d_in[1];
  const float* edge = (const float*)d_in[2];
  const float* hidden = (const float*)d_in[3];
  const float* W1 = (const float*)d_in[4];
  const float* g1 = (const float*)d_in[5];
  const float* b1 = (const float*)d_in[6];
  const float* W2 = (const float*)d_in[7];
  const float* g2 = (const float*)d_in[8];
  const float* b2 = (const float*)d_in[9];
  const float* W3 = (const float*)d_in[10];
  const float* g3 = (const float*)d_in[11];
  const float* b3 = (const float*)d_in[12];
  const float* W4 = (const float*)d_in[13];
  const float* g4 = (const float*)d_in[14];
  const float* b4 = (const float*)d_in[15];
  const float* bias = (const float*)d_in[16];
  const float* Wih = (const float*)d_in[17];
  const float* Whh = (const float*)d_in[18];
  const float* bih = (const float*)d_in[19];
  const float* bhh = (const float*)d_in[20];
  float* out = (float*)d_out;

  const int Nn = in_sizes[0] / 128;   // 4096
  const int E = in_sizes[2] / 16;     // 16384
  const float invE = 1.0f / (float)E;

  float* ws = (float*)d_ws;
  _Float16* y1h = (_Float16*)(ws + 0);         // E x 256 half (8MB) | later gram partials
  float* gpart = ws + 0;                       // 128 x 16384 f32 (8MB) - after y1 consumed... 
  // NOTE: gram partials overlap y1h region only AFTER L2 consumed y1 (true: gram runs post-L3)
  float* ybuf2 = ws + 4194304;                 // y2h (8MB) -> U (f32 8MB) -> gi/gh
  _Float16* y2h = (_Float16*)ybuf2;
  _Float16* y3h = (_Float16*)(ws + 8388608);   // E x 128 half (4MB)
  _Float16* BTf = (_Float16*)(ws + 10485760);  // 128 tiles x 16384 halves (4MB)
  float* t4 = ws + 11534336;                   // 16384
  float* stats = ws + 11550720;                // stat1,stat2,stat3 (3x512) + colsum3 (128)
  float* G3 = ws + 11552512;                   // 16384
  float* sums = ws + 11568896;                 // Nn x 128
  float* cnt = ws + 12093184;                  // Nn
  float* Tn = ws + 12097280;                   // Nn x 128
  float* stat1 = stats, *stat2 = stats + 512, *stat3 = stats + 1024;
  float* colsum3 = stats + 1536;
  float* U = ybuf2;                            // 16384 x 128 f32
  float* gi = ybuf2;                           // 4096 x 384
  float* gh = ybuf2 + 1572864;                 // 4096 x 384

  hipMemsetAsync(stats, 0, 1664 * sizeof(float), stream);
  hipMemsetAsync(sums, 0, ((size_t)Nn * 128 + Nn) * sizeof(float), stream);

  // L1: y1h = edge @ W1^T (+stats1)
  gemm_abt<<<dim3(4, E / 64), 256, 0, stream>>>(edge, W1, y1h, E, 256, 16, stat1, stat1 + 256);
  // L2: y2h = bn1relu(y1h) @ W2^T (+stats2)
  gemm16<1, true, true, true><<<dim3(2, E / 128), 256, 0, stream>>>(
      y1h, W2, y2h, 256, 256, 256, 256, stat1, stat1 + 256, g1, b1, invE, stat2, stat2 + 256);
  // L3: y3h = bn2relu(y2h) @ W3^T (+stats3)
  gemm16<1, true, true, true><<<dim3(1, E / 128), 256, 0, stream>>>(
      y2h, W3, y3h, 256, 256, 128, 256, stat2, stat2 + 256, g2, b2, invE, stat3, stat3 + 256);

  // Gram on bn3relu(y3h) -> partials + colsum3 -> reduce
  gram_kernel<<<E / 128, 256, 0, stream>>>(y3h, gpart, stat3, stat3 + 256, g3, b3, invE,
                                           colsum3);
  gram_reduce<<<64, 256, 0, stream>>>(gpart, G3);

  // U = W4 @ G3
  gemm16<0, false, false, false><<<dim3(1, 16384 / 128), 256, 0, stream>>>(
      W4, G3, U, 128, 128, 128, 128, nullptr, nullptr, nullptr, nullptr, 0.f, nullptr, nullptr);
  w4_finalize<<<16384 / 4, 256, 0, stream>>>(W4, U, colsum3, g4, b4, BTf, t4, invE);
  t4n_kernel<<<Nn / 8, 128, 0, stream>>>(node, t4, Tn, eidx, cnt, E);

  // fused message GEMM (write-ahead pipeline) with direct scatter
  zgemm<<<dim3(4, E / 128), 256, 0, stream>>>(y3h, node, eidx, BTf, Tn,
                                              stat3, stat3 + 256, g3, b3, invE, sums);

  // GRU
  gru_gates<<<dim3(6, Nn / 128), 256, 0, stream>>>(sums, cnt, bias, hidden, Wih, Whh, gi, gh);
  gru_finalize<<<Nn * 128 / 256, 256, 0, stream>>>(gi, gh, hidden, bih, bhh, out, Nn);
}